// Round 7
// baseline (931.257 us; speedup 1.0000x reference)
//
#include <hip/hip_runtime.h>

typedef short v8s __attribute__((ext_vector_type(8)));
typedef float v4f __attribute__((ext_vector_type(4)));

#define S_I 100352

// ---------------- workspace byte offsets (256-aligned) ----------------
#define DEG_B   0ull
#define OFF_B   1605632ull
#define CUR_B   3211264ull
#define CSRS_B  4816896ull
#define FTS_B   16817152ull
#define BSUM_B  31025152ull
#define BPRE_B  31033344ull
#define WT_B    31041536ull
#define WEXT_B  31500288ull
#define VROW_B  31598592ull
#define AEXT_B  31599104ull
#define HA_B    47215104ull
#define ZA_B    104047104ull
#define HO_B    160879104ull
#define WS_NEEDED 192111104ull

__device__ __forceinline__ unsigned short f2bf(float f) {
    unsigned u = __float_as_uint(f);
    u += 0x7fffu + ((u >> 16) & 1u);
    return (unsigned short)(u >> 16);
}
__device__ __forceinline__ float bf2f(unsigned short h) {
    return __uint_as_float(((unsigned)h) << 16);
}

struct IPtr4 { const int* p[4]; };
struct IPtr8 { const int* s[4]; const int* d[4]; };
struct FPtr4 { const float* p[4]; };

// ---------------- degree histogram: 4 edges/thread, fire-and-forget atomics ----------------
__global__ void hist(IPtr4 dst, int* __restrict__ deg) {
    int base = blockIdx.x * 256 + threadIdx.x;
    if (base >= 375000) return;
    int d[4], cb[4];
#pragma unroll
    for (int k = 0; k < 4; k++) {
        int i = base + 375000 * k;
        if (i < 600000)       { cb[k] = 0;       d[k] = dst.p[0][i]; }
        else if (i < 800000)  { cb[k] = S_I;     d[k] = dst.p[1][i - 600000]; }
        else if (i < 1300000) { cb[k] = 2 * S_I; d[k] = dst.p[2][i - 800000]; }
        else                  { cb[k] = 3 * S_I; d[k] = dst.p[3][i - 1300000]; }
    }
#pragma unroll
    for (int k = 0; k < 4; k++) atomicAdd(&deg[cb[k] + d[k]], 1);
}

__device__ __forceinline__ void blk_decode(int b, int& e, int& lb, int& N) {
    if (b < 98)       { e = 0; lb = b;       N = 100000; }
    else if (b < 196) { e = 1; lb = b - 98;  N = 100000; }
    else if (b < 216) { e = 2; lb = b - 196; N = 20000;  }
    else              { e = 3; lb = b - 216; N = 2000;   }
}

__global__ void scan_p1(const int* __restrict__ deg, int* __restrict__ bsum) {
    int tid = threadIdx.x;
    int e, lb, N;
    blk_decode(blockIdx.x, e, lb, N);
    const int* dg = deg + e * S_I;
    int base = lb * 1024 + tid * 4;
    int s = 0;
#pragma unroll
    for (int j = 0; j < 4; j++) { int i = base + j; if (i < N) s += dg[i]; }
    for (int o = 32; o > 0; o >>= 1) s += __shfl_down(s, o);
    __shared__ int wsm[4];
    if ((tid & 63) == 0) wsm[tid >> 6] = s;
    __syncthreads();
    if (tid == 0) bsum[e * 512 + lb] = wsm[0] + wsm[1] + wsm[2] + wsm[3];
}

__global__ void scan_p2(const int* __restrict__ bsum, int* __restrict__ bpre, int* __restrict__ off) {
    __shared__ int sh[256];
    int tid = threadIdx.x;
    for (int e = 0; e < 4; e++) {
        int nb = (e < 2) ? 98 : (e == 2 ? 20 : 2);
        int N  = (e < 2) ? 100000 : (e == 2 ? 20000 : 2000);
        int v = (tid < nb) ? bsum[e * 512 + tid] : 0;
        sh[tid] = v;
        __syncthreads();
        for (int s = 1; s < 256; s <<= 1) {
            int t = (tid >= s) ? sh[tid - s] : 0;
            __syncthreads();
            sh[tid] += t;
            __syncthreads();
        }
        if (tid < nb) bpre[e * 512 + tid] = sh[tid] - v;
        if (tid == 0) off[e * S_I + N] = sh[255];
        __syncthreads();
    }
}

__global__ void scan_p3(const int* __restrict__ deg, const int* __restrict__ bpre,
                        int* __restrict__ off, int* __restrict__ cur) {
    int tid = threadIdx.x;
    int e, lb, N;
    blk_decode(blockIdx.x, e, lb, N);
    const int* dg = deg + e * S_I;
    int base = lb * 1024 + tid * 4;
    int v[4], s = 0;
#pragma unroll
    for (int j = 0; j < 4; j++) { int i = base + j; v[j] = (i < N) ? dg[i] : 0; s += v[j]; }
    int lane = tid & 63, w = tid >> 6;
    int sc = s;
    for (int d = 1; d < 64; d <<= 1) { int t = __shfl_up(sc, d); if (lane >= d) sc += t; }
    __shared__ int wsm[4];
    if (lane == 63) wsm[w] = sc;
    __syncthreads();
    int wpre = 0;
    for (int ww = 0; ww < 4; ww++) if (ww < w) wpre += wsm[ww];
    int run = bpre[e * 512 + lb] + wpre + (sc - s);
#pragma unroll
    for (int j = 0; j < 4; j++) {
        int i = base + j;
        if (i < N) { off[e * S_I + i] = run; cur[e * S_I + i] = run; }
        run += v[j];
    }
}

// ================ MEGA1: fillcsr2 (blocks 0..1464) || h0cvt (1465..29214) || const_build (29215..30303) ================
__global__ void mega1(IPtr8 sd, int* __restrict__ cur, int2* __restrict__ csr2,
                      FPtr4 h, unsigned short* __restrict__ ha,
                      const float* __restrict__ convW, const float* __restrict__ emlpW,
                      const float* __restrict__ emlpb, const float* __restrict__ convb,
                      const float* __restrict__ lnb, unsigned short* __restrict__ wt,
                      unsigned short* __restrict__ wext, float* __restrict__ vrow) {
    int b = blockIdx.x;
    int tid = threadIdx.x;
    if (b < 1465) {
        // ---- fillcsr2: 4 edges/thread ----
        int base = b * 256 + tid;
        if (base >= 375000) return;
        int li[4], eo[4], cb[4], d[4], s[4];
#pragma unroll
        for (int k = 0; k < 4; k++) {
            int i = base + 375000 * k;
            if (i < 600000)       { li[k] = i;           eo[k] = 0;       cb[k] = 0;       d[k] = sd.d[0][li[k]]; s[k] = sd.s[0][li[k]]; }
            else if (i < 800000)  { li[k] = i - 600000;  eo[k] = 600000;  cb[k] = S_I;     d[k] = sd.d[1][li[k]]; s[k] = sd.s[1][li[k]]; }
            else if (i < 1300000) { li[k] = i - 800000;  eo[k] = 800000;  cb[k] = 2 * S_I; d[k] = sd.d[2][li[k]]; s[k] = sd.s[2][li[k]]; }
            else                  { li[k] = i - 1300000; eo[k] = 1300000; cb[k] = 3 * S_I; d[k] = sd.d[3][li[k]]; s[k] = sd.s[3][li[k]]; }
        }
        int p[4];
#pragma unroll
        for (int k = 0; k < 4; k++)
            p[k] = atomicAdd(&cur[cb[k] + d[k]], 1);
#pragma unroll
        for (int k = 0; k < 4; k++)
            csr2[eo[k] + p[k]] = make_int2(s[k], li[k]);
    } else if (b < 29215) {
        // ---- h0cvt ----
        long long i4 = ((long long)(b - 1465) * 256 + tid) * 4;
        if (i4 >= 28416000ll) return;
        long long r = i4 >> 7;
        int c = (int)(i4 & 127);
        int t; long long lr;
        if (r < 100000)      { t = 0; lr = r; }
        else if (r < 120000) { t = 1; lr = r - 100000; }
        else if (r < 122000) { t = 2; lr = r - 120000; }
        else                 { t = 3; lr = r - 122000; }
        const float4 v = *(const float4*)&h.p[t][lr * 128 + c];
        ushort4 o;
        o.x = f2bf(v.x); o.y = f2bf(v.y); o.z = f2bf(v.z); o.w = f2bf(v.w);
        *(ushort4*)&ha[i4] = o;
    } else {
        // ---- const_build ----
        int gid = (b - 29215) * 256 + tid;
        if (gid < 229376) {
            int i = gid;
            int l = i / 114688;
            int rem = i - l * 114688;
            int slot = rem >> 14;
            int idx = rem & 16383;
            int c = idx >> 7, k = idx & 127;
            float v;
            if (slot < 4)
                v = convW[((size_t)(l * 4 + slot) * 256 + 128 + k) * 128 + c];
            else if (slot == 4)
                v = convW[((size_t)(l * 4 + 0) * 256 + k) * 128 + c] +
                    convW[((size_t)(l * 4 + 1) * 256 + k) * 128 + c];
            else
                v = convW[((size_t)(l * 4 + (slot - 3)) * 256 + k) * 128 + c];
            wt[i] = f2bf(v);
        } else if (gid < 229376 + 49152) {
            int g = gid - 229376;
            int slot = g >> 13;
            int rem = g & 8191;
            int c = rem >> 6, r = rem & 63;
            int l = slot / 3, t = slot - l * 3;
            int ef = (t == 0) ? 0 : (t == 1) ? 2 : 3;
            int rr = r & 31, half = r >> 5;
            int e = (t == 0) ? (half ? 1 : 0) : (half ? -1 : ef);
            float v = 0.f;
            if (e >= 0) {
                if (rr < 16)       v = emlpW[e * 2048 + rr * 128 + c];
                else if (rr == 16) v = emlpb[e * 128 + c];
            }
            if (r == 62) {
                v = convb[(l * 4 + ef) * 128 + c];
                if (t == 0) v += convb[(l * 4 + 1) * 128 + c];
            }
            wext[(long long)slot * 8192 + c * 64 + r] = f2bf(v);
        } else if (gid < 229376 + 49152 + 128) {
            int c = gid - 229376 - 49152;
            float s = 0.f;
            for (int k = 0; k < 128; k++)
                s += bf2f(f2bf(lnb[384 + k])) * bf2f(f2bf(convW[((size_t)(1 * 4 + 2) * 256 + 128 + k) * 128 + c]));
            vrow[c] = s;
        }
    }
}

// ================ MEGA2: zgemm l=0 (blocks 0..1736) || ft_gather3 (1737..15611) ================
__global__ __launch_bounds__(256, 2) void mega2(const unsigned short* __restrict__ ha,
        const unsigned short* __restrict__ wt, unsigned short* __restrict__ za,
        const int* __restrict__ off, const int2* __restrict__ csr2,
        FPtr4 ft, float* __restrict__ fts) {
    __shared__ unsigned short As[16384];
    __shared__ unsigned short Bs[16384];
    int tid = threadIdx.x;
    if (blockIdx.x >= 1737) {
        // ---- ft_gather3: 16 lanes per dst row, 4-deep MLP ----
        long long gid = (long long)(blockIdx.x - 1737) * 256 + tid;
        int rid = (int)(gid >> 4), k = (int)(gid & 15);
        if (rid >= 222000) return;
        int e, n, eo;
        if (rid < 100000)      { e = 0; n = rid;          eo = 0; }
        else if (rid < 200000) { e = 1; n = rid - 100000; eo = 600000; }
        else if (rid < 220000) { e = 2; n = rid - 200000; eo = 800000; }
        else                   { e = 3; n = rid - 220000; eo = 1300000; }
        int s = off[e * S_I + n], en = off[e * S_I + n + 1];
        int dg = en - s;
        const int2* ep = csr2 + eo + s;
        const float* fp = ft.p[e];
        float a0 = 0.f, a1 = 0.f, a2 = 0.f, a3 = 0.f;
        int j = 0;
        for (; j + 4 <= dg; j += 4) {
            int e0 = ep[j].y, e1 = ep[j + 1].y, e2 = ep[j + 2].y, e3 = ep[j + 3].y;
            a0 += fp[(long long)e0 * 16 + k];
            a1 += fp[(long long)e1 * 16 + k];
            a2 += fp[(long long)e2 * 16 + k];
            a3 += fp[(long long)e3 * 16 + k];
        }
        if (j + 2 <= dg) {
            int e0 = ep[j].y, e1 = ep[j + 1].y;
            a0 += fp[(long long)e0 * 16 + k];
            a1 += fp[(long long)e1 * 16 + k];
            j += 2;
        }
        if (j < dg) a2 += fp[(long long)ep[j].y * 16 + k];
        fts[(long long)rid * 16 + k] = (a0 + a1) + (a2 + a3);
        return;
    }
    // ---- zgemm, l = 0 ----
    int b = blockIdx.x;
    int e, lb, M; long long aoff, zoff;
    if (b < 157)      { e = 0; lb = b;       M = 20000;  aoff = 100000; zoff = 0; }
    else if (b < 173) { e = 1; lb = b - 157; M = 2000;   aoff = 120000; zoff = 20000; }
    else if (b < 955) { e = 2; lb = b - 173; M = 100000; aoff = 122000; zoff = 22000; }
    else              { e = 3; lb = b - 955; M = 100000; aoff = 0;      zoff = 122000; }
    const unsigned short* A  = ha + aoff * 128;
    const unsigned short* Wt = wt + (size_t)e * 16384;
    unsigned short* outb = za + zoff * 128;
    long long row0 = (long long)lb * 128;
#pragma unroll
    for (int i = 0; i < 8; i++) {
        int idx = tid + i * 256;
        int m = idx >> 4, c = idx & 15;
        int sw = c ^ (m & 15);
        uint4 va = make_uint4(0u, 0u, 0u, 0u);
        long long gr = row0 + m;
        if (gr < M) va = *(const uint4*)&A[gr * 128 + c * 8];
        *(uint4*)&As[m * 128 + sw * 8] = va;
        uint4 wv = *(const uint4*)&Wt[m * 128 + c * 8];
        *(uint4*)&Bs[m * 128 + sw * 8] = wv;
    }
    __syncthreads();
    int lane = tid & 63, w = tid >> 6;
    int q = lane >> 4, ml = lane & 15;
    v4f acc[2][8];
#pragma unroll
    for (int i = 0; i < 2; i++)
#pragma unroll
        for (int j = 0; j < 8; j++) acc[i][j] = (v4f){0.f, 0.f, 0.f, 0.f};
#pragma unroll
    for (int kc = 0; kc < 4; kc++) {
        int ch = (4 * kc + q) ^ ml;
        v8s af[2], bf[8];
#pragma unroll
        for (int i = 0; i < 2; i++) af[i] = *(const v8s*)&As[(32 * w + 16 * i + ml) * 128 + ch * 8];
#pragma unroll
        for (int j = 0; j < 8; j++) bf[j] = *(const v8s*)&Bs[(16 * j + ml) * 128 + ch * 8];
#pragma unroll
        for (int i = 0; i < 2; i++)
#pragma unroll
            for (int j = 0; j < 8; j++)
                acc[i][j] = __builtin_amdgcn_mfma_f32_16x16x32_bf16(af[i], bf[j], acc[i][j], 0, 0, 0);
    }
#pragma unroll
    for (int i = 0; i < 2; i++)
#pragma unroll
        for (int r = 0; r < 4; r++) {
            long long row = row0 + 32 * w + 16 * i + q * 4 + r;
            if (row < M) {
#pragma unroll
                for (int j = 0; j < 8; j++)
                    outb[row * 128 + 16 * j + ml] = f2bf(acc[i][j][r]);
            }
        }
}

// ---------------- pure gather helpers ----------------
__device__ __forceinline__ void acc8(float* t, uint4 v) {
    t[0] += __uint_as_float(v.x << 16);
    t[1] += __uint_as_float(v.x & 0xffff0000u);
    t[2] += __uint_as_float(v.y << 16);
    t[3] += __uint_as_float(v.y & 0xffff0000u);
    t[4] += __uint_as_float(v.z << 16);
    t[5] += __uint_as_float(v.z & 0xffff0000u);
    t[6] += __uint_as_float(v.w << 16);
    t[7] += __uint_as_float(v.w & 0xffff0000u);
}

__device__ __forceinline__ void pull_body(int l, int vb, int tid, const int* __restrict__ off,
        const int2* __restrict__ csr2, const unsigned short* __restrict__ za,
        const float* __restrict__ vrow, unsigned short* __restrict__ hout) {
    long long gid = (long long)vb * 256 + tid;
    int wid = (int)(gid >> 6), lane = (int)(gid & 63);
    if (wid >= 122000) return;
    int t, n;
    if (wid < 100000)      { t = 0; n = wid; }
    else if (wid < 120000) { t = 1; n = wid - 100000; }
    else                   { t = 2; n = wid - 120000; }
    int sub = lane >> 4, k8 = (lane & 15) * 8;
    float a[8];
#pragma unroll
    for (int i = 0; i < 8; i++) a[i] = 0.f;
    int ef = (t == 0) ? 0 : (t == 1) ? 2 : 3;
    int ne = (t == 0) ? 2 : 1;
    for (int ii = 0; ii < ne; ii++) {
        int e = ef + ii;
        int s = off[e * S_I + n], en = off[e * S_I + n + 1];
        int cnt = en - s;
        if (cnt <= 0) continue;
        if (e == 2 && l == 1) {
            if (sub == 0) {
                float4 v0 = *(const float4*)&vrow[k8];
                float4 v1 = *(const float4*)&vrow[k8 + 4];
                a[0] += v0.x; a[1] += v0.y; a[2] += v0.z; a[3] += v0.w;
                a[4] += v1.x; a[5] += v1.y; a[6] += v1.z; a[7] += v1.w;
            }
            continue;
        }
        int eo   = (e == 0) ? 0 : (e == 1) ? 600000 : (e == 2) ? 800000 : 1300000;
        long long zo = (e == 0) ? 0 : (e == 1) ? 20000 : (e == 2) ? 22000 : 122000;
        const int2* cs = csr2 + eo + s;
        const unsigned short* zb = za + zo * 128;
        float t0[8], t1[8];
#pragma unroll
        for (int i = 0; i < 8; i++) { t0[i] = 0.f; t1[i] = 0.f; }
        int j = sub;
        for (; j + 4 < cnt; j += 8) {
            int i0 = cs[j].x, i1 = cs[j + 4].x;
            uint4 v0 = *(const uint4*)&zb[(long long)i0 * 128 + k8];
            uint4 v1 = *(const uint4*)&zb[(long long)i1 * 128 + k8];
            acc8(t0, v0);
            acc8(t1, v1);
        }
        if (j < cnt) {
            int i0 = cs[j].x;
            uint4 v0 = *(const uint4*)&zb[(long long)i0 * 128 + k8];
            acc8(t0, v0);
        }
        float inv = 1.f / (float)cnt;
#pragma unroll
        for (int i = 0; i < 8; i++) a[i] += (t0[i] + t1[i]) * inv;
    }
#pragma unroll
    for (int i = 0; i < 8; i++) {
        a[i] += __shfl_xor(a[i], 16);
        a[i] += __shfl_xor(a[i], 32);
    }
    if (sub == 0) {
        uint4 p;
        p.x = (unsigned)f2bf(a[0]) | ((unsigned)f2bf(a[1]) << 16);
        p.y = (unsigned)f2bf(a[2]) | ((unsigned)f2bf(a[3]) << 16);
        p.z = (unsigned)f2bf(a[4]) | ((unsigned)f2bf(a[5]) << 16);
        p.w = (unsigned)f2bf(a[6]) | ((unsigned)f2bf(a[7]) << 16);
        *(uint4*)&hout[(long long)wid * 128 + k8] = p;
    }
}

// ================ MEGA3: pull_all l=0 (blocks 0..30499) || aext_build (30500..60999) ================
__global__ __launch_bounds__(256) void mega3(const int* __restrict__ off,
        const int2* __restrict__ csr2, const unsigned short* __restrict__ za,
        const float* __restrict__ vrow, unsigned short* __restrict__ ho,
        const float* __restrict__ fts, unsigned short* __restrict__ aext) {
    int tid = threadIdx.x;
    if (blockIdx.x < 30500) {
        pull_body(0, blockIdx.x, tid, off, csr2, za, vrow, ho);
        return;
    }
    // ---- aext_build ----
    int gid = (blockIdx.x - 30500) * 256 + tid;
    if (gid >= 7808000) return;
    int wid = gid >> 6, c = gid & 63;
    int t, n;
    if (wid < 100000)      { t = 0; n = wid; }
    else if (wid < 120000) { t = 1; n = wid - 100000; }
    else                   { t = 2; n = wid - 120000; }
    int cc = c & 31, half = c >> 5;
    int e = -1;
    if (t == 0) e = half ? 1 : 0;
    else if (half == 0) e = (t == 1) ? 2 : 3;
    float v = 0.f;
    if (e >= 0) {
        int s = off[e * S_I + n], en = off[e * S_I + n + 1];
        int dg = en - s;
        if (dg > 0) {
            int fb = (e == 0) ? 0 : (e == 1) ? 100000 : (e == 2) ? 200000 : 220000;
            if (cc < 16)       v = fts[(long long)(fb + n) * 16 + cc] / (float)dg;
            else if (cc == 16) v = 1.f;
        }
    }
    if (c == 62) v = 1.f;
    aext[(long long)wid * 64 + c] = f2bf(v);
}

// ================ MEGA4: pull_all l=1 (blocks 0..30499) || fill_dn (30500..42999) ================
__global__ __launch_bounds__(256) void mega4(const int* __restrict__ off,
        const int2* __restrict__ csr2, const unsigned short* __restrict__ za,
        const float* __restrict__ vrow, unsigned short* __restrict__ ho,
        float* __restrict__ of_dn, const float* __restrict__ lnb3) {
    int tid = threadIdx.x;
    if (blockIdx.x < 30500) {
        pull_body(1, blockIdx.x, tid, off, csr2, za, vrow, ho);
        return;
    }
    // ---- fill_dn ----
    long long i4 = ((long long)(blockIdx.x - 30500) * 256 + tid) * 4;
    if (i4 >= 12800000ll) return;
    int c = (int)(i4 & 127);
    *(float4*)&of_dn[i4] = make_float4(lnb3[c], lnb3[c + 1], lnb3[c + 2], lnb3[c + 3]);
}

// ---------------- merged z-GEMM (layer 1 standalone) ----------------
__global__ __launch_bounds__(256, 2) void zgemm(int l, const unsigned short* __restrict__ ha,
        const unsigned short* __restrict__ wt, unsigned short* __restrict__ za) {
    __shared__ unsigned short As[16384];
    __shared__ unsigned short Bs[16384];
    int b = blockIdx.x;
    int e, lb, M; long long aoff, zoff;
    if (b < 157)      { e = 0; lb = b;       M = 20000;  aoff = 100000; zoff = 0; }
    else if (b < 173) { e = 1; lb = b - 157; M = 2000;   aoff = 120000; zoff = 20000; }
    else              { e = 3; lb = b - 173; M = 100000; aoff = 0;      zoff = 122000; }
    const unsigned short* A  = ha + aoff * 128;
    const unsigned short* Wt = wt + (size_t)(l * 7 + e) * 16384;
    unsigned short* outb = za + zoff * 128;
    int tid = threadIdx.x;
    long long row0 = (long long)lb * 128;
#pragma unroll
    for (int i = 0; i < 8; i++) {
        int idx = tid + i * 256;
        int m = idx >> 4, c = idx & 15;
        int sw = c ^ (m & 15);
        uint4 va = make_uint4(0u, 0u, 0u, 0u);
        long long gr = row0 + m;
        if (gr < M) va = *(const uint4*)&A[gr * 128 + c * 8];
        *(uint4*)&As[m * 128 + sw * 8] = va;
        uint4 wv = *(const uint4*)&Wt[m * 128 + c * 8];
        *(uint4*)&Bs[m * 128 + sw * 8] = wv;
    }
    __syncthreads();
    int lane = tid & 63, w = tid >> 6;
    int q = lane >> 4, ml = lane & 15;
    v4f acc[2][8];
#pragma unroll
    for (int i = 0; i < 2; i++)
#pragma unroll
        for (int j = 0; j < 8; j++) acc[i][j] = (v4f){0.f, 0.f, 0.f, 0.f};
#pragma unroll
    for (int kc = 0; kc < 4; kc++) {
        int ch = (4 * kc + q) ^ ml;
        v8s af[2], bf[8];
#pragma unroll
        for (int i = 0; i < 2; i++) af[i] = *(const v8s*)&As[(32 * w + 16 * i + ml) * 128 + ch * 8];
#pragma unroll
        for (int j = 0; j < 8; j++) bf[j] = *(const v8s*)&Bs[(16 * j + ml) * 128 + ch * 8];
#pragma unroll
        for (int i = 0; i < 2; i++)
#pragma unroll
            for (int j = 0; j < 8; j++)
                acc[i][j] = __builtin_amdgcn_mfma_f32_16x16x32_bf16(af[i], bf[j], acc[i][j], 0, 0, 0);
    }
#pragma unroll
    for (int i = 0; i < 2; i++)
#pragma unroll
        for (int r = 0; r < 4; r++) {
            long long row = row0 + 32 * w + 16 * i + q * 4 + r;
            if (row < M) {
#pragma unroll
                for (int j = 0; j < 8; j++)
                    outb[row * 128 + 16 * j + ml] = f2bf(acc[i][j][r]);
            }
        }
}

// ---------------- merged self-GEMM (K=192 via ext phase) + Cadd + LayerNorm ----------------
__global__ __launch_bounds__(256, 2) void selfgemm(int l, unsigned short* __restrict__ ha,
        const unsigned short* __restrict__ wt, const unsigned short* __restrict__ wext,
        const unsigned short* __restrict__ aext, const unsigned short* __restrict__ ho,
        float* __restrict__ outf, const float* __restrict__ lng, const float* __restrict__ lnb) {
    __shared__ unsigned short As[16384];
    __shared__ unsigned short Bs[16384];
    int b = blockIdx.x;
    int t, lb, M; long long hoff;
    if (b < 782)      { t = 0; lb = b;       M = 100000; hoff = 0; }
    else if (b < 939) { t = 1; lb = b - 782; M = 20000;  hoff = 100000; }
    else              { t = 2; lb = b - 939; M = 2000;   hoff = 120000; }
    const unsigned short* A    = ha + hoff * 128;
    const unsigned short* Ax   = aext + hoff * 64;
    const unsigned short* Wt_  = wt + (size_t)(l * 7 + 4 + t) * 16384;
    const unsigned short* Wx   = wext + (size_t)(l * 3 + t) * 8192;
    const unsigned short* Cadd = ho + hoff * 128;
    const float* g  = lng + t * 128;
    const float* bb = lnb + t * 128;
    int tid = threadIdx.x;
    long long row0 = (long long)lb * 128;
    // phase A: K 0..127
#pragma unroll
    for (int i = 0; i < 8; i++) {
        int idx = tid + i * 256;
        int m = idx >> 4, c = idx & 15;
        int sw = c ^ (m & 15);
        uint4 va = make_uint4(0u, 0u, 0u, 0u);
        long long gr = row0 + m;
        if (gr < M) va = *(const uint4*)&A[gr * 128 + c * 8];
        *(uint4*)&As[m * 128 + sw * 8] = va;
        uint4 wv = *(const uint4*)&Wt_[m * 128 + c * 8];
        *(uint4*)&Bs[m * 128 + sw * 8] = wv;
    }
    __syncthreads();
    int lane = tid & 63, w = tid >> 6;
    int q = lane >> 4, ml = lane & 15;
    v4f acc[2][8];
#pragma unroll
    for (int i = 0; i < 2; i++)
#pragma unroll
        for (int j = 0; j < 8; j++) acc[i][j] = (v4f){0.f, 0.f, 0.f, 0.f};
#pragma unroll
    for (int kc = 0; kc < 4; kc++) {
        int ch = (4 * kc + q) ^ ml;
        v8s af[2], bf[8];
#pragma unroll
        for (int i = 0; i < 2; i++) af[i] = *(const v8s*)&As[(32 * w + 16 * i + ml) * 128 + ch * 8];
#pragma unroll
        for (int j = 0; j < 8; j++) bf[j] = *(const v8s*)&Bs[(16 * j + ml) * 128 + ch * 8];
#pragma unroll
        for (int i = 0; i < 2; i++)
#pragma unroll
            for (int j = 0; j < 8; j++)
                acc[i][j] = __builtin_amdgcn_mfma_f32_16x16x32_bf16(af[i], bf[j], acc[i][j], 0, 0, 0);
    }
    __syncthreads();
    // phase B: K 128..191 (ext)
#pragma unroll
    for (int i = 0; i < 4; i++) {
        int idx = tid + i * 256;
        int m = idx >> 3, c = idx & 7;
        int sw = c ^ (m & 7);
        uint4 va = make_uint4(0u, 0u, 0u, 0u);
        long long gr = row0 + m;
        if (gr < M) va = *(const uint4*)&Ax[gr * 64 + c * 8];
        *(uint4*)&As[m * 64 + sw * 8] = va;
        uint4 wv = *(const uint4*)&Wx[m * 64 + c * 8];
        *(uint4*)&Bs[m * 64 + sw * 8] = wv;
    }
    __syncthreads();
#pragma unroll
    for (int kc = 0; kc < 2; kc++) {
        int ch = (4 * kc + q) ^ (ml & 7);
        v8s af[2], bf[8];
#pragma unroll
        for (int i = 0; i < 2; i++) af[i] = *(const v8s*)&As[(32 * w + 16 * i + ml) * 64 + ch * 8];
#pragma unroll
        for (int j = 0; j < 8; j++) bf[j] = *(const v8s*)&Bs[(16 * j + ml) * 64 + ch * 8];
#pragma unroll
        for (int i = 0; i < 2; i++)
#pragma unroll
            for (int j = 0; j < 8; j++)
                acc[i][j] = __builtin_amdgcn_mfma_f32_16x16x32_bf16(af[i], bf[j], acc[i][j], 0, 0, 0);
    }
    // epilogue: + Cadd (bf16), LayerNorm, store
    float gv[8], bv[8];
#pragma unroll
    for (int j = 0; j < 8; j++) { gv[j] = g[16 * j + ml]; bv[j] = bb[16 * j + ml]; }
    unsigned short* outb = ha + hoff * 128;
    float* outF = outf + hoff * 128;
#pragma unroll
    for (int i = 0; i < 2; i++) {
#pragma unroll
        for (int r = 0; r < 4; r++) {
            long long row = row0 + 32 * w + 16 * i + q * 4 + r;
            bool valid = row < M;
            float s = 0.f, s2 = 0.f;
#pragma unroll
            for (int j = 0; j < 8; j++) {
                float v = acc[i][j][r];
                if (valid) v += bf2f(Cadd[row * 128 + 16 * j + ml]);
                acc[i][j][r] = v;
                s += v; s2 += v * v;
            }
#pragma unroll
            for (int msk = 1; msk < 16; msk <<= 1) {
                s  += __shfl_xor(s,  msk);
                s2 += __shfl_xor(s2, msk);
            }
            float mean = s * 0.0078125f;
            float var  = s2 * 0.0078125f - mean * mean;
            float rs = rsqrtf(var + 1e-5f);
            if (valid) {
#pragma unroll
                for (int j = 0; j < 8; j++) {
                    float v = (acc[i][j][r] - mean) * rs * gv[j] + bv[j];
                    if (l == 0) outb[row * 128 + 16 * j + ml] = f2bf(v);
                    else        outF[row * 128 + 16 * j + ml] = v;
                }
            }
        }
    }
}

// ---------------- host launch ----------------
extern "C" void kernel_launch(void* const* d_in, const int* in_sizes, int n_in,
                              void* d_out, int out_size, void* d_ws, size_t ws_size,
                              hipStream_t stream) {
    if (ws_size < WS_NEEDED) return;

    const float* h0[4] = {(const float*)d_in[0], (const float*)d_in[1],
                          (const float*)d_in[2], (const float*)d_in[3]};
    const float* ftp[4] = {(const float*)d_in[4], (const float*)d_in[5],
                           (const float*)d_in[6], (const float*)d_in[7]};
    const float* convW = (const float*)d_in[8];
    const float* convb = (const float*)d_in[9];
    const float* emlpW = (const float*)d_in[10];
    const float* emlpb = (const float*)d_in[11];
    const float* lng   = (const float*)d_in[12];
    const float* lnb   = (const float*)d_in[13];
    const int* srcp[4] = {(const int*)d_in[14], (const int*)d_in[16],
                          (const int*)d_in[18], (const int*)d_in[20]};
    const int* dstp[4] = {(const int*)d_in[15], (const int*)d_in[17],
                          (const int*)d_in[19], (const int*)d_in[21]};
    char* ws = (char*)d_ws;
    float* out = (float*)d_out;

    int* deg = (int*)(ws + DEG_B);
    int* off = (int*)(ws + OFF_B);
    int* cur = (int*)(ws + CUR_B);
    int2* csr2 = (int2*)(ws + CSRS_B);   // 1.5M x 8B packed (src, eid)
    float* fts = (float*)(ws + FTS_B);
    int* bsum = (int*)(ws + BSUM_B);
    int* bpre = (int*)(ws + BPRE_B);
    unsigned short* wt   = (unsigned short*)(ws + WT_B);
    unsigned short* wext = (unsigned short*)(ws + WEXT_B);
    float* vrow = (float*)(ws + VROW_B);
    unsigned short* aext = (unsigned short*)(ws + AEXT_B);
    unsigned short* ha = (unsigned short*)(ws + HA_B);
    unsigned short* za = (unsigned short*)(ws + ZA_B);
    unsigned short* ho = (unsigned short*)(ws + HO_B);

    hipMemsetAsync(deg, 0, 4 * S_I * sizeof(int), stream);

    IPtr4 dsts; for (int e = 0; e < 4; e++) dsts.p[e] = dstp[e];
    hist<<<1465, 256, 0, stream>>>(dsts, deg);

    scan_p1<<<218, 256, 0, stream>>>(deg, bsum);
    scan_p2<<<1, 256, 0, stream>>>(bsum, bpre, off);
    scan_p3<<<218, 256, 0, stream>>>(deg, bpre, off, cur);

    IPtr8 sd;
    for (int e = 0; e < 4; e++) { sd.s[e] = srcp[e]; sd.d[e] = dstp[e]; }
    FPtr4 hq; for (int t = 0; t < 4; t++) hq.p[t] = h0[t];
    // MEGA1: fillcsr2 || h0cvt || const_build (mutually independent)
    mega1<<<30304, 256, 0, stream>>>(sd, cur, csr2, hq, ha,
                                     convW, emlpW, emlpb, convb, lnb, wt, wext, vrow);

    FPtr4 ftq;  for (int e = 0; e < 4; e++) ftq.p[e] = ftp[e];
    // MEGA2: zgemm(l=0) || ft_gather3 (mutually independent)
    mega2<<<15612, 256, 0, stream>>>(ha, wt, za, off, csr2, ftq, fts);

    // MEGA3: pull_all(l=0) || aext_build
    mega3<<<61000, 256, 0, stream>>>(off, csr2, za, vrow, ho, fts, aext);

    selfgemm<<<955, 256, 0, stream>>>(0, ha, wt, wext, aext, ho, out, lng, lnb);

    zgemm<<<955, 256, 0, stream>>>(1, ha, wt, za);

    // MEGA4: pull_all(l=1) || fill_dn
    mega4<<<43000, 256, 0, stream>>>(off, csr2, za, vrow, ho,
                                     out + 122000ll * 128, lnb + 384);

    selfgemm<<<955, 256, 0, stream>>>(1, ha, wt, wext, aext, ho, out, lng, lnb);
}

// Round 8
// 900.938 us; speedup vs baseline: 1.0337x; 1.0337x over previous
//
#include <hip/hip_runtime.h>

typedef short v8s __attribute__((ext_vector_type(8)));
typedef float v4f __attribute__((ext_vector_type(4)));

#define S_I 100352
#define PAD 16   // one counter per 64B line

// ---------------- workspace byte offsets (256-aligned) ----------------
#define DEG_B   0ull
#define OFF_B   1605632ull
#define CUR_B   3211264ull
#define CSRS_B  4816896ull
#define FTS_B   16817152ull
#define BSUM_B  31025152ull
#define BPRE_B  31033344ull
#define WT_B    31041536ull
#define WEXT_B  31500288ull
#define VROW_B  31598592ull
#define AEXT_B  31599104ull
#define HA_B    47215104ull
#define ZA_B    104047104ull
#define HO_B    160879104ull
#define WS_NEEDED 192111104ull

__device__ __forceinline__ unsigned short f2bf(float f) {
    unsigned u = __float_as_uint(f);
    u += 0x7fffu + ((u >> 16) & 1u);
    return (unsigned short)(u >> 16);
}
__device__ __forceinline__ float bf2f(unsigned short h) {
    return __uint_as_float(((unsigned)h) << 16);
}

struct IPtr4 { const int* p[4]; };
struct IPtr8 { const int* s[4]; const int* d[4]; };
struct FPtr4 { const float* p[4]; };

// ---------------- degree histogram: 4 edges/thread, line-padded counters ----------------
__global__ void hist(IPtr4 dst, int* __restrict__ degp) {
    int base = blockIdx.x * 256 + threadIdx.x;
    if (base >= 375000) return;
    int d[4], cb[4];
#pragma unroll
    for (int k = 0; k < 4; k++) {
        int i = base + 375000 * k;
        if (i < 600000)       { cb[k] = 0;       d[k] = dst.p[0][i]; }
        else if (i < 800000)  { cb[k] = S_I;     d[k] = dst.p[1][i - 600000]; }
        else if (i < 1300000) { cb[k] = 2 * S_I; d[k] = dst.p[2][i - 800000]; }
        else                  { cb[k] = 3 * S_I; d[k] = dst.p[3][i - 1300000]; }
    }
#pragma unroll
    for (int k = 0; k < 4; k++) atomicAdd(&degp[(long long)(cb[k] + d[k]) * PAD], 1);
}

__device__ __forceinline__ void blk_decode(int b, int& e, int& lb, int& N) {
    if (b < 98)       { e = 0; lb = b;       N = 100000; }
    else if (b < 196) { e = 1; lb = b - 98;  N = 100000; }
    else if (b < 216) { e = 2; lb = b - 196; N = 20000;  }
    else              { e = 3; lb = b - 216; N = 2000;   }
}

__global__ void scan_p1(const int* __restrict__ degp, int* __restrict__ bsum) {
    int tid = threadIdx.x;
    int e, lb, N;
    blk_decode(blockIdx.x, e, lb, N);
    const int* dg = degp + (long long)e * S_I * PAD;
    int base = lb * 1024 + tid * 4;
    int s = 0;
#pragma unroll
    for (int j = 0; j < 4; j++) { int i = base + j; if (i < N) s += dg[(long long)i * PAD]; }
    for (int o = 32; o > 0; o >>= 1) s += __shfl_down(s, o);
    __shared__ int wsm[4];
    if ((tid & 63) == 0) wsm[tid >> 6] = s;
    __syncthreads();
    if (tid == 0) bsum[e * 512 + lb] = wsm[0] + wsm[1] + wsm[2] + wsm[3];
}

__global__ void scan_p2(const int* __restrict__ bsum, int* __restrict__ bpre, int* __restrict__ off) {
    __shared__ int sh[256];
    int tid = threadIdx.x;
    for (int e = 0; e < 4; e++) {
        int nb = (e < 2) ? 98 : (e == 2 ? 20 : 2);
        int N  = (e < 2) ? 100000 : (e == 2 ? 20000 : 2000);
        int v = (tid < nb) ? bsum[e * 512 + tid] : 0;
        sh[tid] = v;
        __syncthreads();
        for (int s = 1; s < 256; s <<= 1) {
            int t = (tid >= s) ? sh[tid - s] : 0;
            __syncthreads();
            sh[tid] += t;
            __syncthreads();
        }
        if (tid < nb) bpre[e * 512 + tid] = sh[tid] - v;
        if (tid == 0) off[e * S_I + N] = sh[255];
        __syncthreads();
    }
}

__global__ void scan_p3(const int* __restrict__ degp, const int* __restrict__ bpre,
                        int* __restrict__ off, int* __restrict__ curp) {
    int tid = threadIdx.x;
    int e, lb, N;
    blk_decode(blockIdx.x, e, lb, N);
    const int* dg = degp + (long long)e * S_I * PAD;
    int base = lb * 1024 + tid * 4;
    int v[4], s = 0;
#pragma unroll
    for (int j = 0; j < 4; j++) { int i = base + j; v[j] = (i < N) ? dg[(long long)i * PAD] : 0; s += v[j]; }
    int lane = tid & 63, w = tid >> 6;
    int sc = s;
    for (int d = 1; d < 64; d <<= 1) { int t = __shfl_up(sc, d); if (lane >= d) sc += t; }
    __shared__ int wsm[4];
    if (lane == 63) wsm[w] = sc;
    __syncthreads();
    int wpre = 0;
    for (int ww = 0; ww < 4; ww++) if (ww < w) wpre += wsm[ww];
    int run = bpre[e * 512 + lb] + wpre + (sc - s);
#pragma unroll
    for (int j = 0; j < 4; j++) {
        int i = base + j;
        if (i < N) {
            off[e * S_I + i] = run;
            curp[((long long)e * S_I + i) * PAD] = run;
        }
        run += v[j];
    }
}

// ---------------- CSR fill: 4 edges/thread, line-padded atomic counters ----------------
__global__ void fillcsr2(IPtr8 sd, int* __restrict__ curp, int2* __restrict__ csr2) {
    int base = blockIdx.x * 256 + threadIdx.x;
    if (base >= 375000) return;
    int li[4], eo[4], cb[4], d[4], s[4];
#pragma unroll
    for (int k = 0; k < 4; k++) {
        int i = base + 375000 * k;
        if (i < 600000)       { li[k] = i;           eo[k] = 0;       cb[k] = 0;       d[k] = sd.d[0][li[k]]; s[k] = sd.s[0][li[k]]; }
        else if (i < 800000)  { li[k] = i - 600000;  eo[k] = 600000;  cb[k] = S_I;     d[k] = sd.d[1][li[k]]; s[k] = sd.s[1][li[k]]; }
        else if (i < 1300000) { li[k] = i - 800000;  eo[k] = 800000;  cb[k] = 2 * S_I; d[k] = sd.d[2][li[k]]; s[k] = sd.s[2][li[k]]; }
        else                  { li[k] = i - 1300000; eo[k] = 1300000; cb[k] = 3 * S_I; d[k] = sd.d[3][li[k]]; s[k] = sd.s[3][li[k]]; }
    }
    int p[4];
#pragma unroll
    for (int k = 0; k < 4; k++)
        p[k] = atomicAdd(&curp[(long long)(cb[k] + d[k]) * PAD], 1);
#pragma unroll
    for (int k = 0; k < 4; k++)
        csr2[eo[k] + p[k]] = make_int2(s[k], li[k]);
}

// ---------------- ft segment-sum: 16 lanes per dst row, 4-deep MLP ----------------
__global__ __launch_bounds__(256) void ft_gather3(const int* __restrict__ off,
        const int2* __restrict__ csr2, FPtr4 ft, float* __restrict__ fts) {
    long long gid = (long long)blockIdx.x * 256 + threadIdx.x;
    int rid = (int)(gid >> 4), k = (int)(gid & 15);
    if (rid >= 222000) return;
    int e, n, eo;
    if (rid < 100000)      { e = 0; n = rid;          eo = 0; }
    else if (rid < 200000) { e = 1; n = rid - 100000; eo = 600000; }
    else if (rid < 220000) { e = 2; n = rid - 200000; eo = 800000; }
    else                   { e = 3; n = rid - 220000; eo = 1300000; }
    int s = off[e * S_I + n], en = off[e * S_I + n + 1];
    int dg = en - s;
    const int2* ep = csr2 + eo + s;
    const float* fp = ft.p[e];
    float a0 = 0.f, a1 = 0.f, a2 = 0.f, a3 = 0.f;
    int j = 0;
    for (; j + 4 <= dg; j += 4) {
        int e0 = ep[j].y, e1 = ep[j + 1].y, e2 = ep[j + 2].y, e3 = ep[j + 3].y;
        a0 += fp[(long long)e0 * 16 + k];
        a1 += fp[(long long)e1 * 16 + k];
        a2 += fp[(long long)e2 * 16 + k];
        a3 += fp[(long long)e3 * 16 + k];
    }
    if (j + 2 <= dg) {
        int e0 = ep[j].y, e1 = ep[j + 1].y;
        a0 += fp[(long long)e0 * 16 + k];
        a1 += fp[(long long)e1 * 16 + k];
        j += 2;
    }
    if (j < dg) a2 += fp[(long long)ep[j].y * 16 + k];
    fts[(long long)rid * 16 + k] = (a0 + a1) + (a2 + a3);
}

// merged constant prep: wt tiles + wext + vrow (vrow computed from convW directly)
__global__ void const_build(const float* __restrict__ convW, const float* __restrict__ emlpW,
                            const float* __restrict__ emlpb, const float* __restrict__ convb,
                            const float* __restrict__ lnb, unsigned short* __restrict__ wt,
                            unsigned short* __restrict__ wext, float* __restrict__ vrow) {
    int gid = blockIdx.x * 256 + threadIdx.x;
    if (gid < 229376) {
        int i = gid;
        int l = i / 114688;
        int rem = i - l * 114688;
        int slot = rem >> 14;
        int idx = rem & 16383;
        int c = idx >> 7, k = idx & 127;
        float v;
        if (slot < 4)
            v = convW[((size_t)(l * 4 + slot) * 256 + 128 + k) * 128 + c];
        else if (slot == 4)
            v = convW[((size_t)(l * 4 + 0) * 256 + k) * 128 + c] +
                convW[((size_t)(l * 4 + 1) * 256 + k) * 128 + c];
        else
            v = convW[((size_t)(l * 4 + (slot - 3)) * 256 + k) * 128 + c];
        wt[i] = f2bf(v);
    } else if (gid < 229376 + 49152) {
        int g = gid - 229376;
        int slot = g >> 13;
        int rem = g & 8191;
        int c = rem >> 6, r = rem & 63;
        int l = slot / 3, t = slot - l * 3;
        int ef = (t == 0) ? 0 : (t == 1) ? 2 : 3;
        int rr = r & 31, half = r >> 5;
        int e = (t == 0) ? (half ? 1 : 0) : (half ? -1 : ef);
        float v = 0.f;
        if (e >= 0) {
            if (rr < 16)       v = emlpW[e * 2048 + rr * 128 + c];
            else if (rr == 16) v = emlpb[e * 128 + c];
        }
        if (r == 62) {
            v = convb[(l * 4 + ef) * 128 + c];
            if (t == 0) v += convb[(l * 4 + 1) * 128 + c];
        }
        wext[(long long)slot * 8192 + c * 64 + r] = f2bf(v);
    } else if (gid < 229376 + 49152 + 128) {
        int c = gid - 229376 - 49152;
        // vrow[c] = bf16(lnb3) . bf16(Wbot_e2_l1[:,c])
        float s = 0.f;
        for (int k = 0; k < 128; k++)
            s += bf2f(f2bf(lnb[384 + k])) * bf2f(f2bf(convW[((size_t)(1 * 4 + 2) * 256 + 128 + k) * 128 + c]));
        vrow[c] = s;
    }
}

// A extension [122000][64] bf16: gated mean-ft, gate col, const-1 col 62
__global__ void aext_build(const int* __restrict__ off, const float* __restrict__ fts,
                           unsigned short* __restrict__ aext) {
    int gid = blockIdx.x * 256 + threadIdx.x;
    if (gid >= 7808000) return;
    int wid = gid >> 6, c = gid & 63;
    int t, n;
    if (wid < 100000)      { t = 0; n = wid; }
    else if (wid < 120000) { t = 1; n = wid - 100000; }
    else                   { t = 2; n = wid - 120000; }
    int cc = c & 31, half = c >> 5;
    int e = -1;
    if (t == 0) e = half ? 1 : 0;
    else if (half == 0) e = (t == 1) ? 2 : 3;
    float v = 0.f;
    if (e >= 0) {
        int s = off[e * S_I + n], en = off[e * S_I + n + 1];
        int dg = en - s;
        if (dg > 0) {
            int fb = (e == 0) ? 0 : (e == 1) ? 100000 : (e == 2) ? 200000 : 220000;
            if (cc < 16)       v = fts[(long long)(fb + n) * 16 + cc] / (float)dg;
            else if (cc == 16) v = 1.f;
        }
    }
    if (c == 62) v = 1.f;
    aext[(long long)wid * 64 + c] = f2bf(v);
}

__global__ void h0cvt(FPtr4 h, unsigned short* __restrict__ ha) {
    long long i4 = ((long long)blockIdx.x * 256 + threadIdx.x) * 4;
    if (i4 >= 28416000ll) return;
    long long r = i4 >> 7;
    int c = (int)(i4 & 127);
    int t; long long lr;
    if (r < 100000)      { t = 0; lr = r; }
    else if (r < 120000) { t = 1; lr = r - 100000; }
    else if (r < 122000) { t = 2; lr = r - 120000; }
    else                 { t = 3; lr = r - 122000; }
    const float4 v = *(const float4*)&h.p[t][lr * 128 + c];
    ushort4 o;
    o.x = f2bf(v.x); o.y = f2bf(v.y); o.z = f2bf(v.z); o.w = f2bf(v.w);
    *(ushort4*)&ha[i4] = o;
}

// ---------------- pure gather: ho[n,:] = sum_e mean_z(e,n) ----------------
__device__ __forceinline__ void acc8(float* t, uint4 v) {
    t[0] += __uint_as_float(v.x << 16);
    t[1] += __uint_as_float(v.x & 0xffff0000u);
    t[2] += __uint_as_float(v.y << 16);
    t[3] += __uint_as_float(v.y & 0xffff0000u);
    t[4] += __uint_as_float(v.z << 16);
    t[5] += __uint_as_float(v.z & 0xffff0000u);
    t[6] += __uint_as_float(v.w << 16);
    t[7] += __uint_as_float(v.w & 0xffff0000u);
}

__global__ __launch_bounds__(256) void pull_all(int l, const int* __restrict__ off,
        const int2* __restrict__ csr2, const unsigned short* __restrict__ za,
        const float* __restrict__ vrow, unsigned short* __restrict__ hout) {
    long long gid = (long long)blockIdx.x * 256 + threadIdx.x;
    int wid = (int)(gid >> 6), lane = (int)(gid & 63);
    if (wid >= 122000) return;
    int t, n;
    if (wid < 100000)      { t = 0; n = wid; }
    else if (wid < 120000) { t = 1; n = wid - 100000; }
    else                   { t = 2; n = wid - 120000; }
    int sub = lane >> 4, k8 = (lane & 15) * 8;
    float a[8];
#pragma unroll
    for (int i = 0; i < 8; i++) a[i] = 0.f;
    int ef = (t == 0) ? 0 : (t == 1) ? 2 : 3;
    int ne = (t == 0) ? 2 : 1;
    for (int ii = 0; ii < ne; ii++) {
        int e = ef + ii;
        int s = off[e * S_I + n], en = off[e * S_I + n + 1];
        int cnt = en - s;
        if (cnt <= 0) continue;
        if (e == 2 && l == 1) {
            if (sub == 0) {
                float4 v0 = *(const float4*)&vrow[k8];
                float4 v1 = *(const float4*)&vrow[k8 + 4];
                a[0] += v0.x; a[1] += v0.y; a[2] += v0.z; a[3] += v0.w;
                a[4] += v1.x; a[5] += v1.y; a[6] += v1.z; a[7] += v1.w;
            }
            continue;
        }
        int eo   = (e == 0) ? 0 : (e == 1) ? 600000 : (e == 2) ? 800000 : 1300000;
        long long zo = (e == 0) ? 0 : (e == 1) ? 20000 : (e == 2) ? 22000 : 122000;
        const int2* cs = csr2 + eo + s;
        const unsigned short* zb = za + zo * 128;
        float t0[8], t1[8];
#pragma unroll
        for (int i = 0; i < 8; i++) { t0[i] = 0.f; t1[i] = 0.f; }
        int j = sub;
        for (; j + 4 < cnt; j += 8) {
            int i0 = cs[j].x, i1 = cs[j + 4].x;
            uint4 v0 = *(const uint4*)&zb[(long long)i0 * 128 + k8];
            uint4 v1 = *(const uint4*)&zb[(long long)i1 * 128 + k8];
            acc8(t0, v0);
            acc8(t1, v1);
        }
        if (j < cnt) {
            int i0 = cs[j].x;
            uint4 v0 = *(const uint4*)&zb[(long long)i0 * 128 + k8];
            acc8(t0, v0);
        }
        float inv = 1.f / (float)cnt;
#pragma unroll
        for (int i = 0; i < 8; i++) a[i] += (t0[i] + t1[i]) * inv;
    }
#pragma unroll
    for (int i = 0; i < 8; i++) {
        a[i] += __shfl_xor(a[i], 16);
        a[i] += __shfl_xor(a[i], 32);
    }
    if (sub == 0) {
        uint4 p;
        p.x = (unsigned)f2bf(a[0]) | ((unsigned)f2bf(a[1]) << 16);
        p.y = (unsigned)f2bf(a[2]) | ((unsigned)f2bf(a[3]) << 16);
        p.z = (unsigned)f2bf(a[4]) | ((unsigned)f2bf(a[5]) << 16);
        p.w = (unsigned)f2bf(a[6]) | ((unsigned)f2bf(a[7]) << 16);
        *(uint4*)&hout[(long long)wid * 128 + k8] = p;
    }
}

// ---------------- merged z-GEMM: za = ha @ W_bot (bf16 out), all edge types ----------------
__global__ __launch_bounds__(256, 2) void zgemm(int l, const unsigned short* __restrict__ ha,
        const unsigned short* __restrict__ wt, unsigned short* __restrict__ za) {
    __shared__ unsigned short As[16384];
    __shared__ unsigned short Bs[16384];
    int b = blockIdx.x;
    int e, lb, M; long long aoff, zoff;
    if (l == 0) {
        if (b < 157)      { e = 0; lb = b;       M = 20000;  aoff = 100000; zoff = 0; }
        else if (b < 173) { e = 1; lb = b - 157; M = 2000;   aoff = 120000; zoff = 20000; }
        else if (b < 955) { e = 2; lb = b - 173; M = 100000; aoff = 122000; zoff = 22000; }
        else              { e = 3; lb = b - 955; M = 100000; aoff = 0;      zoff = 122000; }
    } else {
        if (b < 157)      { e = 0; lb = b;       M = 20000;  aoff = 100000; zoff = 0; }
        else if (b < 173) { e = 1; lb = b - 157; M = 2000;   aoff = 120000; zoff = 20000; }
        else              { e = 3; lb = b - 173; M = 100000; aoff = 0;      zoff = 122000; }
    }
    const unsigned short* A  = ha + aoff * 128;
    const unsigned short* Wt = wt + (size_t)(l * 7 + e) * 16384;
    unsigned short* outb = za + zoff * 128;
    int tid = threadIdx.x;
    long long row0 = (long long)lb * 128;
#pragma unroll
    for (int i = 0; i < 8; i++) {
        int idx = tid + i * 256;
        int m = idx >> 4, c = idx & 15;
        int sw = c ^ (m & 15);
        uint4 va = make_uint4(0u, 0u, 0u, 0u);
        long long gr = row0 + m;
        if (gr < M) va = *(const uint4*)&A[gr * 128 + c * 8];
        *(uint4*)&As[m * 128 + sw * 8] = va;
        uint4 wv = *(const uint4*)&Wt[m * 128 + c * 8];
        *(uint4*)&Bs[m * 128 + sw * 8] = wv;
    }
    __syncthreads();
    int lane = tid & 63, w = tid >> 6;
    int q = lane >> 4, ml = lane & 15;
    v4f acc[2][8];
#pragma unroll
    for (int i = 0; i < 2; i++)
#pragma unroll
        for (int j = 0; j < 8; j++) acc[i][j] = (v4f){0.f, 0.f, 0.f, 0.f};
#pragma unroll
    for (int kc = 0; kc < 4; kc++) {
        int ch = (4 * kc + q) ^ ml;
        v8s af[2], bf[8];
#pragma unroll
        for (int i = 0; i < 2; i++) af[i] = *(const v8s*)&As[(32 * w + 16 * i + ml) * 128 + ch * 8];
#pragma unroll
        for (int j = 0; j < 8; j++) bf[j] = *(const v8s*)&Bs[(16 * j + ml) * 128 + ch * 8];
#pragma unroll
        for (int i = 0; i < 2; i++)
#pragma unroll
            for (int j = 0; j < 8; j++)
                acc[i][j] = __builtin_amdgcn_mfma_f32_16x16x32_bf16(af[i], bf[j], acc[i][j], 0, 0, 0);
    }
#pragma unroll
    for (int i = 0; i < 2; i++)
#pragma unroll
        for (int r = 0; r < 4; r++) {
            long long row = row0 + 32 * w + 16 * i + q * 4 + r;
            if (row < M) {
#pragma unroll
                for (int j = 0; j < 8; j++)
                    outb[row * 128 + 16 * j + ml] = f2bf(acc[i][j][r]);
            }
        }
}

// ---------------- merged self-GEMM (K=192 via ext phase) + Cadd + LayerNorm ----------------
__global__ __launch_bounds__(256, 2) void selfgemm(int l, unsigned short* __restrict__ ha,
        const unsigned short* __restrict__ wt, const unsigned short* __restrict__ wext,
        const unsigned short* __restrict__ aext, const unsigned short* __restrict__ ho,
        float* __restrict__ outf, const float* __restrict__ lng, const float* __restrict__ lnb) {
    __shared__ unsigned short As[16384];
    __shared__ unsigned short Bs[16384];
    int b = blockIdx.x;
    int t, lb, M; long long hoff;
    if (b < 782)      { t = 0; lb = b;       M = 100000; hoff = 0; }
    else if (b < 939) { t = 1; lb = b - 782; M = 20000;  hoff = 100000; }
    else              { t = 2; lb = b - 939; M = 2000;   hoff = 120000; }
    const unsigned short* A    = ha + hoff * 128;
    const unsigned short* Ax   = aext + hoff * 64;
    const unsigned short* Wt_  = wt + (size_t)(l * 7 + 4 + t) * 16384;
    const unsigned short* Wx   = wext + (size_t)(l * 3 + t) * 8192;
    const unsigned short* Cadd = ho + hoff * 128;
    const float* g  = lng + t * 128;
    const float* bb = lnb + t * 128;
    int tid = threadIdx.x;
    long long row0 = (long long)lb * 128;
    // phase A: K 0..127
#pragma unroll
    for (int i = 0; i < 8; i++) {
        int idx = tid + i * 256;
        int m = idx >> 4, c = idx & 15;
        int sw = c ^ (m & 15);
        uint4 va = make_uint4(0u, 0u, 0u, 0u);
        long long gr = row0 + m;
        if (gr < M) va = *(const uint4*)&A[gr * 128 + c * 8];
        *(uint4*)&As[m * 128 + sw * 8] = va;
        uint4 wv = *(const uint4*)&Wt_[m * 128 + c * 8];
        *(uint4*)&Bs[m * 128 + sw * 8] = wv;
    }
    __syncthreads();
    int lane = tid & 63, w = tid >> 6;
    int q = lane >> 4, ml = lane & 15;
    v4f acc[2][8];
#pragma unroll
    for (int i = 0; i < 2; i++)
#pragma unroll
        for (int j = 0; j < 8; j++) acc[i][j] = (v4f){0.f, 0.f, 0.f, 0.f};
#pragma unroll
    for (int kc = 0; kc < 4; kc++) {
        int ch = (4 * kc + q) ^ ml;
        v8s af[2], bf[8];
#pragma unroll
        for (int i = 0; i < 2; i++) af[i] = *(const v8s*)&As[(32 * w + 16 * i + ml) * 128 + ch * 8];
#pragma unroll
        for (int j = 0; j < 8; j++) bf[j] = *(const v8s*)&Bs[(16 * j + ml) * 128 + ch * 8];
#pragma unroll
        for (int i = 0; i < 2; i++)
#pragma unroll
            for (int j = 0; j < 8; j++)
                acc[i][j] = __builtin_amdgcn_mfma_f32_16x16x32_bf16(af[i], bf[j], acc[i][j], 0, 0, 0);
    }
    __syncthreads();
    // phase B: K 128..191 (ext)
#pragma unroll
    for (int i = 0; i < 4; i++) {
        int idx = tid + i * 256;
        int m = idx >> 3, c = idx & 7;
        int sw = c ^ (m & 7);
        uint4 va = make_uint4(0u, 0u, 0u, 0u);
        long long gr = row0 + m;
        if (gr < M) va = *(const uint4*)&Ax[gr * 64 + c * 8];
        *(uint4*)&As[m * 64 + sw * 8] = va;
        uint4 wv = *(const uint4*)&Wx[m * 64 + c * 8];
        *(uint4*)&Bs[m * 64 + sw * 8] = wv;
    }
    __syncthreads();
#pragma unroll
    for (int kc = 0; kc < 2; kc++) {
        int ch = (4 * kc + q) ^ (ml & 7);
        v8s af[2], bf[8];
#pragma unroll
        for (int i = 0; i < 2; i++) af[i] = *(const v8s*)&As[(32 * w + 16 * i + ml) * 64 + ch * 8];
#pragma unroll
        for (int j = 0; j < 8; j++) bf[j] = *(const v8s*)&Bs[(16 * j + ml) * 64 + ch * 8];
#pragma unroll
        for (int i = 0; i < 2; i++)
#pragma unroll
            for (int j = 0; j < 8; j++)
                acc[i][j] = __builtin_amdgcn_mfma_f32_16x16x32_bf16(af[i], bf[j], acc[i][j], 0, 0, 0);
    }
    // epilogue: + Cadd (bf16), LayerNorm, store
    float gv[8], bv[8];
#pragma unroll
    for (int j = 0; j < 8; j++) { gv[j] = g[16 * j + ml]; bv[j] = bb[16 * j + ml]; }
    unsigned short* outb = ha + hoff * 128;
    float* outF = outf + hoff * 128;
#pragma unroll
    for (int i = 0; i < 2; i++) {
#pragma unroll
        for (int r = 0; r < 4; r++) {
            long long row = row0 + 32 * w + 16 * i + q * 4 + r;
            bool valid = row < M;
            float s = 0.f, s2 = 0.f;
#pragma unroll
            for (int j = 0; j < 8; j++) {
                float v = acc[i][j][r];
                if (valid) v += bf2f(Cadd[row * 128 + 16 * j + ml]);
                acc[i][j][r] = v;
                s += v; s2 += v * v;
            }
#pragma unroll
            for (int msk = 1; msk < 16; msk <<= 1) {
                s  += __shfl_xor(s,  msk);
                s2 += __shfl_xor(s2, msk);
            }
            float mean = s * 0.0078125f;
            float var  = s2 * 0.0078125f - mean * mean;
            float rs = rsqrtf(var + 1e-5f);
            if (valid) {
#pragma unroll
                for (int j = 0; j < 8; j++) {
                    float v = (acc[i][j][r] - mean) * rs * gv[j] + bv[j];
                    if (l == 0) outb[row * 128 + 16 * j + ml] = f2bf(v);
                    else        outF[row * 128 + 16 * j + ml] = v;
                }
            }
        }
    }
}

__global__ void fill_dn(float* __restrict__ of, const float* __restrict__ lnb3) {
    long long i4 = ((long long)blockIdx.x * 256 + threadIdx.x) * 4;
    if (i4 >= 12800000ll) return;
    int c = (int)(i4 & 127);
    *(float4*)&of[i4] = make_float4(lnb3[c], lnb3[c + 1], lnb3[c + 2], lnb3[c + 3]);
}

// ---------------- host launch ----------------
extern "C" void kernel_launch(void* const* d_in, const int* in_sizes, int n_in,
                              void* d_out, int out_size, void* d_ws, size_t ws_size,
                              hipStream_t stream) {
    if (ws_size < WS_NEEDED) return;

    const float* h0[4] = {(const float*)d_in[0], (const float*)d_in[1],
                          (const float*)d_in[2], (const float*)d_in[3]};
    const float* ftp[4] = {(const float*)d_in[4], (const float*)d_in[5],
                           (const float*)d_in[6], (const float*)d_in[7]};
    const float* convW = (const float*)d_in[8];
    const float* convb = (const float*)d_in[9];
    const float* emlpW = (const float*)d_in[10];
    const float* emlpb = (const float*)d_in[11];
    const float* lng   = (const float*)d_in[12];
    const float* lnb   = (const float*)d_in[13];
    const int* srcp[4] = {(const int*)d_in[14], (const int*)d_in[16],
                          (const int*)d_in[18], (const int*)d_in[20]};
    const int* dstp[4] = {(const int*)d_in[15], (const int*)d_in[17],
                          (const int*)d_in[19], (const int*)d_in[21]};
    char* ws = (char*)d_ws;
    float* out = (float*)d_out;

    int* off = (int*)(ws + OFF_B);
    int2* csr2 = (int2*)(ws + CSRS_B);   // 1.5M x 8B packed (src, eid)
    float* fts = (float*)(ws + FTS_B);
    int* bsum = (int*)(ws + BSUM_B);
    int* bpre = (int*)(ws + BPRE_B);
    unsigned short* wt   = (unsigned short*)(ws + WT_B);
    unsigned short* wext = (unsigned short*)(ws + WEXT_B);
    float* vrow = (float*)(ws + VROW_B);
    unsigned short* aext = (unsigned short*)(ws + AEXT_B);
    unsigned short* ha = (unsigned short*)(ws + HA_B);
    unsigned short* za = (unsigned short*)(ws + ZA_B);
    unsigned short* ho = (unsigned short*)(ws + HO_B);
    // line-padded counters (25.7 MB each) alias the za region: dead until
    // zgemm(l=0), which launches strictly after fillcsr2 (stream-ordered).
    int* degp = (int*)(ws + ZA_B);                                  // 4*S_I*16 ints
    int* curp = (int*)(ws + ZA_B + (unsigned long long)4 * S_I * PAD * 4);

    hipMemsetAsync(degp, 0, (size_t)4 * S_I * PAD * sizeof(int), stream);

    IPtr4 dsts; for (int e = 0; e < 4; e++) dsts.p[e] = dstp[e];
    hist<<<1465, 256, 0, stream>>>(dsts, degp);

    scan_p1<<<218, 256, 0, stream>>>(degp, bsum);
    scan_p2<<<1, 256, 0, stream>>>(bsum, bpre, off);
    scan_p3<<<218, 256, 0, stream>>>(degp, bpre, off, curp);
    IPtr8 sd;
    for (int e = 0; e < 4; e++) { sd.s[e] = srcp[e]; sd.d[e] = dstp[e]; }
    fillcsr2<<<1465, 256, 0, stream>>>(sd, curp, csr2);

    FPtr4 ftq;  for (int e = 0; e < 4; e++) ftq.p[e] = ftp[e];
    ft_gather3<<<13875, 256, 0, stream>>>(off, csr2, ftq, fts);

    const_build<<<1089, 256, 0, stream>>>(convW, emlpW, emlpb, convb, lnb, wt, wext, vrow);
    FPtr4 hq; for (int t = 0; t < 4; t++) hq.p[t] = h0[t];
    h0cvt<<<27750, 256, 0, stream>>>(hq, ha);
    aext_build<<<30500, 256, 0, stream>>>(off, fts, aext);

    for (int l = 0; l < 2; l++) {
        zgemm<<<(l == 0) ? 1737 : 955, 256, 0, stream>>>(l, ha, wt, za);
        pull_all<<<30500, 256, 0, stream>>>(l, off, csr2, za, vrow, ho);
        selfgemm<<<955, 256, 0, stream>>>(l, ha, wt, wext, aext, ho, out, lng, lnb);
    }
    fill_dn<<<12500, 256, 0, stream>>>(out + 122000ll * 128, lnb + 384);
}

// Round 9
// 811.983 us; speedup vs baseline: 1.1469x; 1.1096x over previous
//
#include <hip/hip_runtime.h>

typedef short v8s __attribute__((ext_vector_type(8)));
typedef float v4f __attribute__((ext_vector_type(4)));

#define S_I 100352

// ---------------- workspace byte offsets (256-aligned) ----------------
#define DEG_B   0ull
#define OFF_B   1605632ull
#define CUR_B   3211264ull
#define CSRS_B  4816896ull
#define FTS_B   16817152ull
#define BSUM_B  31025152ull
#define BPRE_B  31033344ull
#define WT_B    31041536ull
#define WEXT_B  31500288ull
#define VROW_B  31598592ull
#define AEXT_B  31599104ull
#define HA_B    47215104ull
#define ZA_B    104047104ull
#define HO_B    160879104ull
#define WS_NEEDED 192111104ull

__device__ __forceinline__ unsigned short f2bf(float f) {
    unsigned u = __float_as_uint(f);
    u += 0x7fffu + ((u >> 16) & 1u);
    return (unsigned short)(u >> 16);
}
__device__ __forceinline__ float bf2f(unsigned short h) {
    return __uint_as_float(((unsigned)h) << 16);
}

struct IPtr4 { const int* p[4]; };
struct IPtr8 { const int* s[4]; const int* d[4]; };
struct FPtr4 { const float* p[4]; };

// ---------------- rank pass: THE single atomic pass ----------------
// r[i] = arrival rank among same-(e,dst) edges; final cnt == degree histogram.
__global__ void rank_k(IPtr4 dst, int* __restrict__ cnt, int* __restrict__ rnk) {
    int i = blockIdx.x * 256 + threadIdx.x;
    if (i >= 1500000) return;
    int e, li;
    if (i < 600000)       { e = 0; li = i; }
    else if (i < 800000)  { e = 1; li = i - 600000; }
    else if (i < 1300000) { e = 2; li = i - 800000; }
    else                  { e = 3; li = i - 1300000; }
    int d = dst.p[e][li];
    rnk[i] = atomicAdd(&cnt[e * S_I + d], 1);
}

__device__ __forceinline__ void blk_decode(int b, int& e, int& lb, int& N) {
    if (b < 98)       { e = 0; lb = b;       N = 100000; }
    else if (b < 196) { e = 1; lb = b - 98;  N = 100000; }
    else if (b < 216) { e = 2; lb = b - 196; N = 20000;  }
    else              { e = 3; lb = b - 216; N = 2000;   }
}

__global__ void scan_p1(const int* __restrict__ cnt, int* __restrict__ bsum) {
    int tid = threadIdx.x;
    int e, lb, N;
    blk_decode(blockIdx.x, e, lb, N);
    const int* dg = cnt + e * S_I;
    int base = lb * 1024 + tid * 4;
    int s = 0;
#pragma unroll
    for (int j = 0; j < 4; j++) { int i = base + j; if (i < N) s += dg[i]; }
    for (int o = 32; o > 0; o >>= 1) s += __shfl_down(s, o);
    __shared__ int wsm[4];
    if ((tid & 63) == 0) wsm[tid >> 6] = s;
    __syncthreads();
    if (tid == 0) bsum[e * 512 + lb] = wsm[0] + wsm[1] + wsm[2] + wsm[3];
}

__global__ void scan_p2(const int* __restrict__ bsum, int* __restrict__ bpre, int* __restrict__ off) {
    __shared__ int sh[256];
    int tid = threadIdx.x;
    for (int e = 0; e < 4; e++) {
        int nb = (e < 2) ? 98 : (e == 2 ? 20 : 2);
        int N  = (e < 2) ? 100000 : (e == 2 ? 20000 : 2000);
        int v = (tid < nb) ? bsum[e * 512 + tid] : 0;
        sh[tid] = v;
        __syncthreads();
        for (int s = 1; s < 256; s <<= 1) {
            int t = (tid >= s) ? sh[tid - s] : 0;
            __syncthreads();
            sh[tid] += t;
            __syncthreads();
        }
        if (tid < nb) bpre[e * 512 + tid] = sh[tid] - v;
        if (tid == 0) off[e * S_I + N] = sh[255];
        __syncthreads();
    }
}

__global__ void scan_p3(const int* __restrict__ cnt, const int* __restrict__ bpre,
                        int* __restrict__ off) {
    int tid = threadIdx.x;
    int e, lb, N;
    blk_decode(blockIdx.x, e, lb, N);
    const int* dg = cnt + e * S_I;
    int base = lb * 1024 + tid * 4;
    int v[4], s = 0;
#pragma unroll
    for (int j = 0; j < 4; j++) { int i = base + j; v[j] = (i < N) ? dg[i] : 0; s += v[j]; }
    int lane = tid & 63, w = tid >> 6;
    int sc = s;
    for (int d = 1; d < 64; d <<= 1) { int t = __shfl_up(sc, d); if (lane >= d) sc += t; }
    __shared__ int wsm[4];
    if (lane == 63) wsm[w] = sc;
    __syncthreads();
    int wpre = 0;
    for (int ww = 0; ww < 4; ww++) if (ww < w) wpre += wsm[ww];
    int run = bpre[e * 512 + lb] + wpre + (sc - s);
#pragma unroll
    for (int j = 0; j < 4; j++) {
        int i = base + j;
        if (i < N) off[e * S_I + i] = run;
        run += v[j];
    }
}

// ---------------- placement pass: pure streaming, NO atomics ----------------
__global__ void place_k(IPtr8 sd, const int* __restrict__ off, const int* __restrict__ rnk,
                        int2* __restrict__ csr2) {
    int i = blockIdx.x * 256 + threadIdx.x;
    if (i >= 1500000) return;
    int e, li, eo;
    if (i < 600000)       { e = 0; li = i;           eo = 0; }
    else if (i < 800000)  { e = 1; li = i - 600000;  eo = 600000; }
    else if (i < 1300000) { e = 2; li = i - 800000;  eo = 800000; }
    else                  { e = 3; li = i - 1300000; eo = 1300000; }
    int d = sd.d[e][li];
    int pos = off[e * S_I + d] + rnk[i];
    csr2[eo + pos] = make_int2(sd.s[e][li], li);
}

// ---------------- ft segment-sum: 16 lanes per dst row, 4-deep MLP ----------------
__global__ __launch_bounds__(256) void ft_gather3(const int* __restrict__ off,
        const int2* __restrict__ csr2, FPtr4 ft, float* __restrict__ fts) {
    long long gid = (long long)blockIdx.x * 256 + threadIdx.x;
    int rid = (int)(gid >> 4), k = (int)(gid & 15);
    if (rid >= 222000) return;
    int e, n, eo;
    if (rid < 100000)      { e = 0; n = rid;          eo = 0; }
    else if (rid < 200000) { e = 1; n = rid - 100000; eo = 600000; }
    else if (rid < 220000) { e = 2; n = rid - 200000; eo = 800000; }
    else                   { e = 3; n = rid - 220000; eo = 1300000; }
    int s = off[e * S_I + n], en = off[e * S_I + n + 1];
    int dg = en - s;
    const int2* ep = csr2 + eo + s;
    const float* fp = ft.p[e];
    float a0 = 0.f, a1 = 0.f, a2 = 0.f, a3 = 0.f;
    int j = 0;
    for (; j + 4 <= dg; j += 4) {
        int e0 = ep[j].y, e1 = ep[j + 1].y, e2 = ep[j + 2].y, e3 = ep[j + 3].y;
        a0 += fp[(long long)e0 * 16 + k];
        a1 += fp[(long long)e1 * 16 + k];
        a2 += fp[(long long)e2 * 16 + k];
        a3 += fp[(long long)e3 * 16 + k];
    }
    if (j + 2 <= dg) {
        int e0 = ep[j].y, e1 = ep[j + 1].y;
        a0 += fp[(long long)e0 * 16 + k];
        a1 += fp[(long long)e1 * 16 + k];
        j += 2;
    }
    if (j < dg) a2 += fp[(long long)ep[j].y * 16 + k];
    fts[(long long)rid * 16 + k] = (a0 + a1) + (a2 + a3);
}

// merged constant prep: wt tiles + wext + vrow (vrow computed from convW directly)
__global__ void const_build(const float* __restrict__ convW, const float* __restrict__ emlpW,
                            const float* __restrict__ emlpb, const float* __restrict__ convb,
                            const float* __restrict__ lnb, unsigned short* __restrict__ wt,
                            unsigned short* __restrict__ wext, float* __restrict__ vrow) {
    int gid = blockIdx.x * 256 + threadIdx.x;
    if (gid < 229376) {
        int i = gid;
        int l = i / 114688;
        int rem = i - l * 114688;
        int slot = rem >> 14;
        int idx = rem & 16383;
        int c = idx >> 7, k = idx & 127;
        float v;
        if (slot < 4)
            v = convW[((size_t)(l * 4 + slot) * 256 + 128 + k) * 128 + c];
        else if (slot == 4)
            v = convW[((size_t)(l * 4 + 0) * 256 + k) * 128 + c] +
                convW[((size_t)(l * 4 + 1) * 256 + k) * 128 + c];
        else
            v = convW[((size_t)(l * 4 + (slot - 3)) * 256 + k) * 128 + c];
        wt[i] = f2bf(v);
    } else if (gid < 229376 + 49152) {
        int g = gid - 229376;
        int slot = g >> 13;
        int rem = g & 8191;
        int c = rem >> 6, r = rem & 63;
        int l = slot / 3, t = slot - l * 3;
        int ef = (t == 0) ? 0 : (t == 1) ? 2 : 3;
        int rr = r & 31, half = r >> 5;
        int e = (t == 0) ? (half ? 1 : 0) : (half ? -1 : ef);
        float v = 0.f;
        if (e >= 0) {
            if (rr < 16)       v = emlpW[e * 2048 + rr * 128 + c];
            else if (rr == 16) v = emlpb[e * 128 + c];
        }
        if (r == 62) {
            v = convb[(l * 4 + ef) * 128 + c];
            if (t == 0) v += convb[(l * 4 + 1) * 128 + c];
        }
        wext[(long long)slot * 8192 + c * 64 + r] = f2bf(v);
    } else if (gid < 229376 + 49152 + 128) {
        int c = gid - 229376 - 49152;
        // vrow[c] = bf16(lnb3) . bf16(Wbot_e2_l1[:,c])
        float s = 0.f;
        for (int k = 0; k < 128; k++)
            s += bf2f(f2bf(lnb[384 + k])) * bf2f(f2bf(convW[((size_t)(1 * 4 + 2) * 256 + 128 + k) * 128 + c]));
        vrow[c] = s;
    }
}

// A extension [122000][64] bf16: gated mean-ft, gate col, const-1 col 62
__global__ void aext_build(const int* __restrict__ off, const float* __restrict__ fts,
                           unsigned short* __restrict__ aext) {
    int gid = blockIdx.x * 256 + threadIdx.x;
    if (gid >= 7808000) return;
    int wid = gid >> 6, c = gid & 63;
    int t, n;
    if (wid < 100000)      { t = 0; n = wid; }
    else if (wid < 120000) { t = 1; n = wid - 100000; }
    else                   { t = 2; n = wid - 120000; }
    int cc = c & 31, half = c >> 5;
    int e = -1;
    if (t == 0) e = half ? 1 : 0;
    else if (half == 0) e = (t == 1) ? 2 : 3;
    float v = 0.f;
    if (e >= 0) {
        int s = off[e * S_I + n], en = off[e * S_I + n + 1];
        int dg = en - s;
        if (dg > 0) {
            int fb = (e == 0) ? 0 : (e == 1) ? 100000 : (e == 2) ? 200000 : 220000;
            if (cc < 16)       v = fts[(long long)(fb + n) * 16 + cc] / (float)dg;
            else if (cc == 16) v = 1.f;
        }
    }
    if (c == 62) v = 1.f;
    aext[(long long)wid * 64 + c] = f2bf(v);
}

__global__ void h0cvt(FPtr4 h, unsigned short* __restrict__ ha) {
    long long i4 = ((long long)blockIdx.x * 256 + threadIdx.x) * 4;
    if (i4 >= 28416000ll) return;
    long long r = i4 >> 7;
    int c = (int)(i4 & 127);
    int t; long long lr;
    if (r < 100000)      { t = 0; lr = r; }
    else if (r < 120000) { t = 1; lr = r - 100000; }
    else if (r < 122000) { t = 2; lr = r - 120000; }
    else                 { t = 3; lr = r - 122000; }
    const float4 v = *(const float4*)&h.p[t][lr * 128 + c];
    ushort4 o;
    o.x = f2bf(v.x); o.y = f2bf(v.y); o.z = f2bf(v.z); o.w = f2bf(v.w);
    *(ushort4*)&ha[i4] = o;
}

// ---------------- pure gather: ho[n,:] = sum_e mean_z(e,n) ----------------
__device__ __forceinline__ void acc8(float* t, uint4 v) {
    t[0] += __uint_as_float(v.x << 16);
    t[1] += __uint_as_float(v.x & 0xffff0000u);
    t[2] += __uint_as_float(v.y << 16);
    t[3] += __uint_as_float(v.y & 0xffff0000u);
    t[4] += __uint_as_float(v.z << 16);
    t[5] += __uint_as_float(v.z & 0xffff0000u);
    t[6] += __uint_as_float(v.w << 16);
    t[7] += __uint_as_float(v.w & 0xffff0000u);
}

__global__ __launch_bounds__(256) void pull_all(int l, const int* __restrict__ off,
        const int2* __restrict__ csr2, const unsigned short* __restrict__ za,
        const float* __restrict__ vrow, unsigned short* __restrict__ hout) {
    long long gid = (long long)blockIdx.x * 256 + threadIdx.x;
    int wid = (int)(gid >> 6), lane = (int)(gid & 63);
    if (wid >= 122000) return;
    int t, n;
    if (wid < 100000)      { t = 0; n = wid; }
    else if (wid < 120000) { t = 1; n = wid - 100000; }
    else                   { t = 2; n = wid - 120000; }
    int sub = lane >> 4, k8 = (lane & 15) * 8;
    float a[8];
#pragma unroll
    for (int i = 0; i < 8; i++) a[i] = 0.f;
    int ef = (t == 0) ? 0 : (t == 1) ? 2 : 3;
    int ne = (t == 0) ? 2 : 1;
    for (int ii = 0; ii < ne; ii++) {
        int e = ef + ii;
        int s = off[e * S_I + n], en = off[e * S_I + n + 1];
        int cnt = en - s;
        if (cnt <= 0) continue;
        if (e == 2 && l == 1) {
            if (sub == 0) {
                float4 v0 = *(const float4*)&vrow[k8];
                float4 v1 = *(const float4*)&vrow[k8 + 4];
                a[0] += v0.x; a[1] += v0.y; a[2] += v0.z; a[3] += v0.w;
                a[4] += v1.x; a[5] += v1.y; a[6] += v1.z; a[7] += v1.w;
            }
            continue;
        }
        int eo   = (e == 0) ? 0 : (e == 1) ? 600000 : (e == 2) ? 800000 : 1300000;
        long long zo = (e == 0) ? 0 : (e == 1) ? 20000 : (e == 2) ? 22000 : 122000;
        const int2* cs = csr2 + eo + s;
        const unsigned short* zb = za + zo * 128;
        float t0[8], t1[8];
#pragma unroll
        for (int i = 0; i < 8; i++) { t0[i] = 0.f; t1[i] = 0.f; }
        int j = sub;
        for (; j + 4 < cnt; j += 8) {
            int i0 = cs[j].x, i1 = cs[j + 4].x;
            uint4 v0 = *(const uint4*)&zb[(long long)i0 * 128 + k8];
            uint4 v1 = *(const uint4*)&zb[(long long)i1 * 128 + k8];
            acc8(t0, v0);
            acc8(t1, v1);
        }
        if (j < cnt) {
            int i0 = cs[j].x;
            uint4 v0 = *(const uint4*)&zb[(long long)i0 * 128 + k8];
            acc8(t0, v0);
        }
        float inv = 1.f / (float)cnt;
#pragma unroll
        for (int i = 0; i < 8; i++) a[i] += (t0[i] + t1[i]) * inv;
    }
#pragma unroll
    for (int i = 0; i < 8; i++) {
        a[i] += __shfl_xor(a[i], 16);
        a[i] += __shfl_xor(a[i], 32);
    }
    if (sub == 0) {
        uint4 p;
        p.x = (unsigned)f2bf(a[0]) | ((unsigned)f2bf(a[1]) << 16);
        p.y = (unsigned)f2bf(a[2]) | ((unsigned)f2bf(a[3]) << 16);
        p.z = (unsigned)f2bf(a[4]) | ((unsigned)f2bf(a[5]) << 16);
        p.w = (unsigned)f2bf(a[6]) | ((unsigned)f2bf(a[7]) << 16);
        *(uint4*)&hout[(long long)wid * 128 + k8] = p;
    }
}

// ---------------- merged z-GEMM: za = ha @ W_bot (bf16 out), all edge types ----------------
__global__ __launch_bounds__(256, 2) void zgemm(int l, const unsigned short* __restrict__ ha,
        const unsigned short* __restrict__ wt, unsigned short* __restrict__ za) {
    __shared__ unsigned short As[16384];
    __shared__ unsigned short Bs[16384];
    int b = blockIdx.x;
    int e, lb, M; long long aoff, zoff;
    if (l == 0) {
        if (b < 157)      { e = 0; lb = b;       M = 20000;  aoff = 100000; zoff = 0; }
        else if (b < 173) { e = 1; lb = b - 157; M = 2000;   aoff = 120000; zoff = 20000; }
        else if (b < 955) { e = 2; lb = b - 173; M = 100000; aoff = 122000; zoff = 22000; }
        else              { e = 3; lb = b - 955; M = 100000; aoff = 0;      zoff = 122000; }
    } else {
        if (b < 157)      { e = 0; lb = b;       M = 20000;  aoff = 100000; zoff = 0; }
        else if (b < 173) { e = 1; lb = b - 157; M = 2000;   aoff = 120000; zoff = 20000; }
        else              { e = 3; lb = b - 173; M = 100000; aoff = 0;      zoff = 122000; }
    }
    const unsigned short* A  = ha + aoff * 128;
    const unsigned short* Wt = wt + (size_t)(l * 7 + e) * 16384;
    unsigned short* outb = za + zoff * 128;
    int tid = threadIdx.x;
    long long row0 = (long long)lb * 128;
#pragma unroll
    for (int i = 0; i < 8; i++) {
        int idx = tid + i * 256;
        int m = idx >> 4, c = idx & 15;
        int sw = c ^ (m & 15);
        uint4 va = make_uint4(0u, 0u, 0u, 0u);
        long long gr = row0 + m;
        if (gr < M) va = *(const uint4*)&A[gr * 128 + c * 8];
        *(uint4*)&As[m * 128 + sw * 8] = va;
        uint4 wv = *(const uint4*)&Wt[m * 128 + c * 8];
        *(uint4*)&Bs[m * 128 + sw * 8] = wv;
    }
    __syncthreads();
    int lane = tid & 63, w = tid >> 6;
    int q = lane >> 4, ml = lane & 15;
    v4f acc[2][8];
#pragma unroll
    for (int i = 0; i < 2; i++)
#pragma unroll
        for (int j = 0; j < 8; j++) acc[i][j] = (v4f){0.f, 0.f, 0.f, 0.f};
#pragma unroll
    for (int kc = 0; kc < 4; kc++) {
        int ch = (4 * kc + q) ^ ml;
        v8s af[2], bf[8];
#pragma unroll
        for (int i = 0; i < 2; i++) af[i] = *(const v8s*)&As[(32 * w + 16 * i + ml) * 128 + ch * 8];
#pragma unroll
        for (int j = 0; j < 8; j++) bf[j] = *(const v8s*)&Bs[(16 * j + ml) * 128 + ch * 8];
#pragma unroll
        for (int i = 0; i < 2; i++)
#pragma unroll
            for (int j = 0; j < 8; j++)
                acc[i][j] = __builtin_amdgcn_mfma_f32_16x16x32_bf16(af[i], bf[j], acc[i][j], 0, 0, 0);
    }
#pragma unroll
    for (int i = 0; i < 2; i++)
#pragma unroll
        for (int r = 0; r < 4; r++) {
            long long row = row0 + 32 * w + 16 * i + q * 4 + r;
            if (row < M) {
#pragma unroll
                for (int j = 0; j < 8; j++)
                    outb[row * 128 + 16 * j + ml] = f2bf(acc[i][j][r]);
            }
        }
}

// ---------------- merged self-GEMM (K=192 via ext phase) + Cadd + LayerNorm ----------------
__global__ __launch_bounds__(256, 2) void selfgemm(int l, unsigned short* __restrict__ ha,
        const unsigned short* __restrict__ wt, const unsigned short* __restrict__ wext,
        const unsigned short* __restrict__ aext, const unsigned short* __restrict__ ho,
        float* __restrict__ outf, const float* __restrict__ lng, const float* __restrict__ lnb) {
    __shared__ unsigned short As[16384];
    __shared__ unsigned short Bs[16384];
    int b = blockIdx.x;
    int t, lb, M; long long hoff;
    if (b < 782)      { t = 0; lb = b;       M = 100000; hoff = 0; }
    else if (b < 939) { t = 1; lb = b - 782; M = 20000;  hoff = 100000; }
    else              { t = 2; lb = b - 939; M = 2000;   hoff = 120000; }
    const unsigned short* A    = ha + hoff * 128;
    const unsigned short* Ax   = aext + hoff * 64;
    const unsigned short* Wt_  = wt + (size_t)(l * 7 + 4 + t) * 16384;
    const unsigned short* Wx   = wext + (size_t)(l * 3 + t) * 8192;
    const unsigned short* Cadd = ho + hoff * 128;
    const float* g  = lng + t * 128;
    const float* bb = lnb + t * 128;
    int tid = threadIdx.x;
    long long row0 = (long long)lb * 128;
    // phase A: K 0..127
#pragma unroll
    for (int i = 0; i < 8; i++) {
        int idx = tid + i * 256;
        int m = idx >> 4, c = idx & 15;
        int sw = c ^ (m & 15);
        uint4 va = make_uint4(0u, 0u, 0u, 0u);
        long long gr = row0 + m;
        if (gr < M) va = *(const uint4*)&A[gr * 128 + c * 8];
        *(uint4*)&As[m * 128 + sw * 8] = va;
        uint4 wv = *(const uint4*)&Wt_[m * 128 + c * 8];
        *(uint4*)&Bs[m * 128 + sw * 8] = wv;
    }
    __syncthreads();
    int lane = tid & 63, w = tid >> 6;
    int q = lane >> 4, ml = lane & 15;
    v4f acc[2][8];
#pragma unroll
    for (int i = 0; i < 2; i++)
#pragma unroll
        for (int j = 0; j < 8; j++) acc[i][j] = (v4f){0.f, 0.f, 0.f, 0.f};
#pragma unroll
    for (int kc = 0; kc < 4; kc++) {
        int ch = (4 * kc + q) ^ ml;
        v8s af[2], bf[8];
#pragma unroll
        for (int i = 0; i < 2; i++) af[i] = *(const v8s*)&As[(32 * w + 16 * i + ml) * 128 + ch * 8];
#pragma unroll
        for (int j = 0; j < 8; j++) bf[j] = *(const v8s*)&Bs[(16 * j + ml) * 128 + ch * 8];
#pragma unroll
        for (int i = 0; i < 2; i++)
#pragma unroll
            for (int j = 0; j < 8; j++)
                acc[i][j] = __builtin_amdgcn_mfma_f32_16x16x32_bf16(af[i], bf[j], acc[i][j], 0, 0, 0);
    }
    __syncthreads();
    // phase B: K 128..191 (ext)
#pragma unroll
    for (int i = 0; i < 4; i++) {
        int idx = tid + i * 256;
        int m = idx >> 3, c = idx & 7;
        int sw = c ^ (m & 7);
        uint4 va = make_uint4(0u, 0u, 0u, 0u);
        long long gr = row0 + m;
        if (gr < M) va = *(const uint4*)&Ax[gr * 64 + c * 8];
        *(uint4*)&As[m * 64 + sw * 8] = va;
        uint4 wv = *(const uint4*)&Wx[m * 64 + c * 8];
        *(uint4*)&Bs[m * 64 + sw * 8] = wv;
    }
    __syncthreads();
#pragma unroll
    for (int kc = 0; kc < 2; kc++) {
        int ch = (4 * kc + q) ^ (ml & 7);
        v8s af[2], bf[8];
#pragma unroll
        for (int i = 0; i < 2; i++) af[i] = *(const v8s*)&As[(32 * w + 16 * i + ml) * 64 + ch * 8];
#pragma unroll
        for (int j = 0; j < 8; j++) bf[j] = *(const v8s*)&Bs[(16 * j + ml) * 64 + ch * 8];
#pragma unroll
        for (int i = 0; i < 2; i++)
#pragma unroll
            for (int j = 0; j < 8; j++)
                acc[i][j] = __builtin_amdgcn_mfma_f32_16x16x32_bf16(af[i], bf[j], acc[i][j], 0, 0, 0);
    }
    // epilogue: + Cadd (bf16), LayerNorm, store
    float gv[8], bv[8];
#pragma unroll
    for (int j = 0; j < 8; j++) { gv[j] = g[16 * j + ml]; bv[j] = bb[16 * j + ml]; }
    unsigned short* outb = ha + hoff * 128;
    float* outF = outf + hoff * 128;
#pragma unroll
    for (int i = 0; i < 2; i++) {
#pragma unroll
        for (int r = 0; r < 4; r++) {
            long long row = row0 + 32 * w + 16 * i + q * 4 + r;
            bool valid = row < M;
            float s = 0.f, s2 = 0.f;
#pragma unroll
            for (int j = 0; j < 8; j++) {
                float v = acc[i][j][r];
                if (valid) v += bf2f(Cadd[row * 128 + 16 * j + ml]);
                acc[i][j][r] = v;
                s += v; s2 += v * v;
            }
#pragma unroll
            for (int msk = 1; msk < 16; msk <<= 1) {
                s  += __shfl_xor(s,  msk);
                s2 += __shfl_xor(s2, msk);
            }
            float mean = s * 0.0078125f;
            float var  = s2 * 0.0078125f - mean * mean;
            float rs = rsqrtf(var + 1e-5f);
            if (valid) {
#pragma unroll
                for (int j = 0; j < 8; j++) {
                    float v = (acc[i][j][r] - mean) * rs * gv[j] + bv[j];
                    if (l == 0) outb[row * 128 + 16 * j + ml] = f2bf(v);
                    else        outF[row * 128 + 16 * j + ml] = v;
                }
            }
        }
    }
}

__global__ void fill_dn(float* __restrict__ of, const float* __restrict__ lnb3) {
    long long i4 = ((long long)blockIdx.x * 256 + threadIdx.x) * 4;
    if (i4 >= 12800000ll) return;
    int c = (int)(i4 & 127);
    *(float4*)&of[i4] = make_float4(lnb3[c], lnb3[c + 1], lnb3[c + 2], lnb3[c + 3]);
}

// ---------------- host launch ----------------
extern "C" void kernel_launch(void* const* d_in, const int* in_sizes, int n_in,
                              void* d_out, int out_size, void* d_ws, size_t ws_size,
                              hipStream_t stream) {
    if (ws_size < WS_NEEDED) return;

    const float* h0[4] = {(const float*)d_in[0], (const float*)d_in[1],
                          (const float*)d_in[2], (const float*)d_in[3]};
    const float* ftp[4] = {(const float*)d_in[4], (const float*)d_in[5],
                           (const float*)d_in[6], (const float*)d_in[7]};
    const float* convW = (const float*)d_in[8];
    const float* convb = (const float*)d_in[9];
    const float* emlpW = (const float*)d_in[10];
    const float* emlpb = (const float*)d_in[11];
    const float* lng   = (const float*)d_in[12];
    const float* lnb   = (const float*)d_in[13];
    const int* srcp[4] = {(const int*)d_in[14], (const int*)d_in[16],
                          (const int*)d_in[18], (const int*)d_in[20]};
    const int* dstp[4] = {(const int*)d_in[15], (const int*)d_in[17],
                          (const int*)d_in[19], (const int*)d_in[21]};
    char* ws = (char*)d_ws;
    float* out = (float*)d_out;

    int* cnt = (int*)(ws + DEG_B);       // dense counters; final value = degree
    int* off = (int*)(ws + OFF_B);
    int2* csr2 = (int2*)(ws + CSRS_B);   // 1.5M x 8B packed (src, eid)
    float* fts = (float*)(ws + FTS_B);
    int* bsum = (int*)(ws + BSUM_B);
    int* bpre = (int*)(ws + BPRE_B);
    unsigned short* wt   = (unsigned short*)(ws + WT_B);
    unsigned short* wext = (unsigned short*)(ws + WEXT_B);
    float* vrow = (float*)(ws + VROW_B);
    unsigned short* aext = (unsigned short*)(ws + AEXT_B);
    unsigned short* ha = (unsigned short*)(ws + HA_B);
    unsigned short* za = (unsigned short*)(ws + ZA_B);
    unsigned short* ho = (unsigned short*)(ws + HO_B);
    // rnk (6 MB) aliases the za region: dead until zgemm(l=0), which launches
    // strictly after place_k (stream-ordered).
    int* rnk = (int*)(ws + ZA_B);

    hipMemsetAsync(cnt, 0, 4 * S_I * sizeof(int), stream);

    IPtr4 dsts; for (int e = 0; e < 4; e++) dsts.p[e] = dstp[e];
    // single atomic pass: ranks + counts together
    rank_k<<<5860, 256, 0, stream>>>(dsts, cnt, rnk);

    scan_p1<<<218, 256, 0, stream>>>(cnt, bsum);
    scan_p2<<<1, 256, 0, stream>>>(bsum, bpre, off);
    scan_p3<<<218, 256, 0, stream>>>(cnt, bpre, off);

    IPtr8 sd;
    for (int e = 0; e < 4; e++) { sd.s[e] = srcp[e]; sd.d[e] = dstp[e]; }
    // atomic-free placement
    place_k<<<5860, 256, 0, stream>>>(sd, off, rnk, csr2);

    FPtr4 ftq;  for (int e = 0; e < 4; e++) ftq.p[e] = ftp[e];
    ft_gather3<<<13875, 256, 0, stream>>>(off, csr2, ftq, fts);

    const_build<<<1089, 256, 0, stream>>>(convW, emlpW, emlpb, convb, lnb, wt, wext, vrow);
    FPtr4 hq; for (int t = 0; t < 4; t++) hq.p[t] = h0[t];
    h0cvt<<<27750, 256, 0, stream>>>(hq, ha);
    aext_build<<<30500, 256, 0, stream>>>(off, fts, aext);

    for (int l = 0; l < 2; l++) {
        zgemm<<<(l == 0) ? 1737 : 955, 256, 0, stream>>>(l, ha, wt, za);
        pull_all<<<30500, 256, 0, stream>>>(l, off, csr2, za, vrow, ho);
        selfgemm<<<955, 256, 0, stream>>>(l, ha, wt, wext, aext, ho, out, lng, lnb);
    }
    fill_dn<<<12500, 256, 0, stream>>>(out + 122000ll * 128, lnb + 384);
}